// Round 3
// baseline (193.924 us; speedup 1.0000x reference)
//
#include <hip/hip_runtime.h>
#include <cstdint>
#include <cstddef>

#define BB 8
#define NN 2048
#define FF 128
#define HH 128
#define SS 2
#define NT (NN / 64)

typedef _Float16 f16x8 __attribute__((ext_vector_type(8)));
typedef _Float16 f16x4 __attribute__((ext_vector_type(4)));
typedef float f32x4 __attribute__((ext_vector_type(4)));

// ---------------------------------------------------------------------------
// geo: g1[s][i][j] = mask (f16), g2[s][i][j] = mask*inv_d (f32, exact div)
// ---------------------------------------------------------------------------
__global__ __launch_bounds__(256) void geo_kernel(
    const float* __restrict__ dist, const float* __restrict__ sigmas,
    const float* __restrict__ thr, _Float16* __restrict__ g1, float* __restrict__ g2)
{
    const size_t idx = ((size_t)blockIdx.x * 256 + threadIdx.x) * 8;
    const int s = (int)(idx >> 22);
    const int i = (int)((idx >> 11) & (NN - 1));
    const int j0 = (int)(idx & (NN - 1));
    const float sg = sigmas[s];
    const float inv2s2 = 1.0f / (2.0f * sg * sg);
    const float th = thr[s];
    const float* dp = dist + (size_t)i * NN + j0;
    float4 d0 = *(const float4*)dp, d1 = *(const float4*)(dp + 4);
    float dv[8] = {d0.x, d0.y, d0.z, d0.w, d1.x, d1.y, d1.z, d1.w};
    f16x8 o1; float og[8];
    #pragma unroll
    for (int k = 0; k < 8; ++k) {
        float d = dv[k];
        float A = __expf(-d * d * inv2s2);
        float msk = 1.0f / (1.0f + __expf(-10.0f * (A - th)));
        float dd = (j0 + k == i) ? 1.0f : d;
        float invd = 1.0f / (dd + 1e-5f);
        o1[k] = (_Float16)msk;
        og[k] = msk * invd;
    }
    *(f16x8*)(g1 + idx) = o1;
    *(float4*)(g2 + idx)     = (float4){og[0], og[1], og[2], og[3]};
    *(float4*)(g2 + idx + 4) = (float4){og[4], og[5], og[6], og[7]};
}

// ---------------------------------------------------------------------------
// prep: h = X@W^T (+Wb) via fp16 MFMA -> h_t[sb][ch][n] f16.
// si/sj computed from the MFMA accumulators (k0 merged): 16-lane shfl reduce
// over lm, cross-wave reduce in LDS.
// LDS: Xs [64][256B] @0 (16KB), Wt [128][256B] @16384 (32KB), sred @49152 (2KB)
// ---------------------------------------------------------------------------
__global__ __launch_bounds__(256, 2) void prep_kernel(
    const float* __restrict__ X, const float* __restrict__ Ww, const float* __restrict__ Wb,
    const float* __restrict__ ai, const float* __restrict__ aj, const float* __restrict__ ab,
    _Float16* __restrict__ h_t, float* __restrict__ srow, float* __restrict__ scol)
{
    const int s = blockIdx.z, b = blockIdx.y;
    const int n0 = blockIdx.x * 64;
    const int tid = threadIdx.x;
    __shared__ __align__(16) unsigned char smem[51200];
    float* sredI = (float*)(smem + 49152);          // [4][64]
    float* sredJ = (float*)(smem + 49152 + 1024);   // [4][64]

    {   // stage Xs (fp32 -> f16, swizzled)
        const int r = tid >> 2, fq = tid & 3;
        const float* src = X + ((size_t)b * NN + n0 + r) * FF + fq * 32;
        unsigned char* dst = smem + r * 256;
        const unsigned rs = r & 15;
        #pragma unroll
        for (int k = 0; k < 4; ++k) {
            float4 v0 = *(const float4*)(src + k * 8);
            float4 v1 = *(const float4*)(src + k * 8 + 4);
            f16x8 h;
            h[0]=(_Float16)v0.x; h[1]=(_Float16)v0.y; h[2]=(_Float16)v0.z; h[3]=(_Float16)v0.w;
            h[4]=(_Float16)v1.x; h[5]=(_Float16)v1.y; h[6]=(_Float16)v1.z; h[7]=(_Float16)v1.w;
            *(f16x8*)(dst + (((fq * 4 + k) ^ rs) << 4)) = h;
        }
    }
    {   // stage Wt (fp32 -> f16, swizzled)
        const int ch = tid >> 1, kh8 = (tid & 1) * 8;
        const float* src = Ww + ((size_t)s * HH + ch) * FF + kh8 * 8;
        unsigned char* dst = smem + 16384 + ch * 256;
        const unsigned cs = ch & 15;
        #pragma unroll
        for (int k = 0; k < 8; ++k) {
            float4 v0 = *(const float4*)(src + k * 8);
            float4 v1 = *(const float4*)(src + k * 8 + 4);
            f16x8 h;
            h[0]=(_Float16)v0.x; h[1]=(_Float16)v0.y; h[2]=(_Float16)v0.z; h[3]=(_Float16)v0.w;
            h[4]=(_Float16)v1.x; h[5]=(_Float16)v1.y; h[6]=(_Float16)v1.z; h[7]=(_Float16)v1.w;
            *(f16x8*)(dst + (((kh8 + k) ^ cs) << 4)) = h;
        }
    }
    __syncthreads();

    const int wave = tid >> 6, lane = tid & 63;
    const int lm = lane & 15, lq = lane >> 4;
    f32x4 acc[4][2];
    #pragma unroll
    for (int m = 0; m < 4; ++m)
        #pragma unroll
        for (int n = 0; n < 2; ++n) acc[m][n] = (f32x4){0.f, 0.f, 0.f, 0.f};

    #pragma unroll
    for (int ks = 0; ks < 4; ++ks) {
        f16x8 af[4], bf[2];
        #pragma unroll
        for (int m = 0; m < 4; ++m) {
            int r = m * 16 + lm;
            af[m] = *(const f16x8*)(smem + r * 256 + ((((ks << 2) | lq) ^ (r & 15)) << 4));
        }
        #pragma unroll
        for (int n = 0; n < 2; ++n) {
            int ch = wave * 32 + n * 16 + lm;
            bf[n] = *(const f16x8*)(smem + 16384 + ch * 256 + ((((ks << 2) | lq) ^ (ch & 15)) << 4));
        }
        #pragma unroll
        for (int m = 0; m < 4; ++m)
            #pragma unroll
            for (int n = 0; n < 2; ++n)
                acc[m][n] = __builtin_amdgcn_mfma_f32_16x16x32_f16(af[m], bf[n], acc[m][n], 0, 0, 0);
    }

    const float wb0 = Wb[s * HH + wave * 32 + lm];
    const float wb1 = Wb[s * HH + wave * 32 + 16 + lm];
    const float ai0 = ai[s * HH + wave * 32 + lm];
    const float ai1 = ai[s * HH + wave * 32 + 16 + lm];
    const float aj0 = aj[s * HH + wave * 32 + lm];
    const float aj1 = aj[s * HH + wave * 32 + 16 + lm];
    float pI[4][4], pJ[4][4];
    #pragma unroll
    for (int m = 0; m < 4; ++m) {
        #pragma unroll
        for (int r = 0; r < 4; ++r) {
            float h0 = acc[m][0][r] + wb0;
            float h1 = acc[m][1][r] + wb1;
            pI[m][r] = h0 * ai0 + h1 * ai1;
            pJ[m][r] = h0 * aj0 + h1 * aj1;
        }
        #pragma unroll
        for (int n = 0; n < 2; ++n) {
            float wb = n ? wb1 : wb0;
            f16x4 hv;
            #pragma unroll
            for (int r = 0; r < 4; ++r) hv[r] = (_Float16)(acc[m][n][r] + wb);
            int ch = wave * 32 + n * 16 + lm;
            *(f16x4*)(h_t + ((size_t)((s * BB + b) * HH + ch)) * NN + n0 + m * 16 + lq * 4) = hv;
        }
    }
    #pragma unroll
    for (int st = 1; st < 16; st <<= 1) {
        #pragma unroll
        for (int m = 0; m < 4; ++m)
            #pragma unroll
            for (int r = 0; r < 4; ++r) {
                pI[m][r] += __shfl_xor(pI[m][r], st);
                pJ[m][r] += __shfl_xor(pJ[m][r], st);
            }
    }
    if (lm == 0) {
        #pragma unroll
        for (int m = 0; m < 4; ++m)
            #pragma unroll
            for (int r = 0; r < 4; ++r) {
                sredI[wave * 64 + m * 16 + lq * 4 + r] = pI[m][r];
                sredJ[wave * 64 + m * 16 + lq * 4 + r] = pJ[m][r];
            }
    }
    __syncthreads();
    if (tid < 64) {
        float sI = sredI[tid] + sredI[64 + tid] + sredI[128 + tid] + sredI[192 + tid] + ab[s];
        float sJ = sredJ[tid] + sredJ[64 + tid] + sredJ[128 + tid] + sredJ[192 + tid];
        size_t idx = (size_t)(s * BB + b) * NN + n0 + tid;
        srow[idx] = sI;
        scol[idx] = sJ;
    }
}

// ---------------------------------------------------------------------------
// attn: pipelined flash. TM=32 rows, TK=64. ONE barrier per j-tile.
// Window(jt): [issue reg-prefetch jt+1] [MFMA jt-1 from buf (jt-1)&1]
//             [phase-1 jt from regs -> buf jt&1] [barrier].
// LDS: P dbuf 2x4KB @0, h dbuf 2x16KB @8192, sc dbuf 2x128B @40960, l @41216.
// All tiles 128B rows with 3-bit XOR swizzle (2-way max on r/w).
// ---------------------------------------------------------------------------
template<bool GEO>
__global__ __launch_bounds__(256, 3) void attn_kernel(
    const float* __restrict__ dist, const float* __restrict__ sigmas,
    const float* __restrict__ thr, const _Float16* __restrict__ h_t,
    const float* __restrict__ srow, const float* __restrict__ scol,
    const _Float16* __restrict__ g1, const float* __restrict__ g2,
    _Float16* __restrict__ Hcat)
{
    const int s = blockIdx.z, b = blockIdx.y;
    const int i0 = blockIdx.x * 32;
    const int tid = threadIdx.x;

    __shared__ __align__(16) unsigned char smem[41344];
    float* scb    = (float*)(smem + 40960);   // [2][32]
    float* lrow_s = (float*)(smem + 41216);   // [32]

    const size_t sb = (size_t)(s * BB + b) * NN;
    const _Float16* hbase = h_t + (size_t)(s * BB + b) * HH * NN;

    const int wave = tid >> 6, lane = tid & 63;
    const int lm = lane & 15, lq = lane >> 4;
    const int chq = wave;

    // phase-1 geometry: 32 rows x 8 j-groups of 8
    const int row = tid >> 3, jg = tid & 7, jg8 = jg * 8;
    const int gi = i0 + row;
    const unsigned rsw = row & 7;
    const float si = srow[sb + gi];
    const size_t girow = ((size_t)s * NN + gi) * NN;
    const size_t drow = (size_t)gi * NN;

    // h-stage geometry
    const int sch = tid >> 1, shf4 = (tid & 1) * 4;
    const _Float16* hrow = hbase + (size_t)sch * NN + (shf4 >> 2) * 32;
    const unsigned hsw = sch & 7;

    float inv2s2 = 0.f, th = 0.f;
    if (!GEO) { float sg = sigmas[s]; inv2s2 = 1.0f / (2.0f * sg * sg); th = thr[s]; }

    f32x4 acc[2][2];
    #pragma unroll
    for (int m = 0; m < 2; ++m)
        #pragma unroll
        for (int n = 0; n < 2; ++n) acc[m][n] = (f32x4){0.f, 0.f, 0.f, 0.f};
    float m_r = -3.0e38f, l_r = 0.f;

    f16x8 hA[4], hB[4], gA, gB;
    f32x4 qA[2], qB[2];

#define LOADT(HT, GT, QT, J0V) {                                              \
    const _Float16* hp_ = hrow + (J0V);                                       \
    HT[0] = *(const f16x8*)(hp_);                                             \
    HT[1] = *(const f16x8*)(hp_ + 8);                                         \
    HT[2] = *(const f16x8*)(hp_ + 16);                                        \
    HT[3] = *(const f16x8*)(hp_ + 24);                                        \
    const int jb_ = (J0V) + jg8;                                              \
    if (GEO) {                                                                \
        GT = *(const f16x8*)(g1 + girow + jb_);                               \
        QT[0] = *(const f32x4*)(g2 + girow + jb_);                            \
        QT[1] = *(const f32x4*)(g2 + girow + jb_ + 4);                        \
    } else {                                                                  \
        (void)GT;                                                             \
        QT[0] = *(const f32x4*)(dist + drow + jb_);                           \
        QT[1] = *(const f32x4*)(dist + drow + jb_ + 4);                       \
    }                                                                         \
}

#define MFMA_STEP(MB) {                                                       \
    f16x8 af00, af01, af10, af11, bf00, bf01, bf10, bf11;                     \
    { const unsigned char* pb_ = smem + (MB) * 4096;                          \
      int r_ = lm; unsigned sw_ = r_ & 7;                                     \
      af00 = *(const f16x8*)(pb_ + r_ * 128 + ((lq ^ sw_) << 4));             \
      af01 = *(const f16x8*)(pb_ + r_ * 128 + (((4 | lq) ^ sw_) << 4));       \
      r_ = 16 + lm; sw_ = r_ & 7;                                             \
      af10 = *(const f16x8*)(pb_ + r_ * 128 + ((lq ^ sw_) << 4));             \
      af11 = *(const f16x8*)(pb_ + r_ * 128 + (((4 | lq) ^ sw_) << 4)); }     \
    { const unsigned char* hb_ = smem + 8192 + (MB) * 16384;                  \
      int c_ = chq * 32 + lm; unsigned sw_ = c_ & 7;                          \
      bf00 = *(const f16x8*)(hb_ + c_ * 128 + ((lq ^ sw_) << 4));             \
      bf01 = *(const f16x8*)(hb_ + c_ * 128 + (((4 | lq) ^ sw_) << 4));       \
      c_ = chq * 32 + 16 + lm; sw_ = c_ & 7;                                  \
      bf10 = *(const f16x8*)(hb_ + c_ * 128 + ((lq ^ sw_) << 4));             \
      bf11 = *(const f16x8*)(hb_ + c_ * 128 + (((4 | lq) ^ sw_) << 4)); }     \
    f32x4 sc0 = *(const f32x4*)(scb + (MB) * 32 + lq * 4);                    \
    f32x4 sc1 = *(const f32x4*)(scb + (MB) * 32 + 16 + lq * 4);               \
    acc[0][0] *= sc0; acc[0][1] *= sc0;                                       \
    acc[1][0] *= sc1; acc[1][1] *= sc1;                                       \
    acc[0][0] = __builtin_amdgcn_mfma_f32_16x16x32_f16(af00, bf00, acc[0][0], 0, 0, 0); \
    acc[0][0] = __builtin_amdgcn_mfma_f32_16x16x32_f16(af01, bf01, acc[0][0], 0, 0, 0); \
    acc[0][1] = __builtin_amdgcn_mfma_f32_16x16x32_f16(af00, bf10, acc[0][1], 0, 0, 0); \
    acc[0][1] = __builtin_amdgcn_mfma_f32_16x16x32_f16(af01, bf11, acc[0][1], 0, 0, 0); \
    acc[1][0] = __builtin_amdgcn_mfma_f32_16x16x32_f16(af10, bf00, acc[1][0], 0, 0, 0); \
    acc[1][0] = __builtin_amdgcn_mfma_f32_16x16x32_f16(af11, bf01, acc[1][0], 0, 0, 0); \
    acc[1][1] = __builtin_amdgcn_mfma_f32_16x16x32_f16(af10, bf10, acc[1][1], 0, 0, 0); \
    acc[1][1] = __builtin_amdgcn_mfma_f32_16x16x32_f16(af11, bf11, acc[1][1], 0, 0, 0); \
}

#define PHASE1(HC, GC, QC, J0, PB) {                                          \
    unsigned char* hd_ = smem + 8192 + (PB) * 16384 + sch * 128;              \
    *(f16x8*)(hd_ + (((shf4 + 0) ^ hsw) << 4)) = HC[0];                       \
    *(f16x8*)(hd_ + (((shf4 + 1) ^ hsw) << 4)) = HC[1];                       \
    *(f16x8*)(hd_ + (((shf4 + 2) ^ hsw) << 4)) = HC[2];                       \
    *(f16x8*)(hd_ + (((shf4 + 3) ^ hsw) << 4)) = HC[3];                       \
    const int jb_ = (J0) + jg8;                                               \
    f32x4 c0_ = *(const f32x4*)(scol + sb + jb_);                             \
    f32x4 c1_ = *(const f32x4*)(scol + sb + jb_ + 4);                         \
    float ev[8];                                                              \
    if (GEO) {                                                                \
        _Pragma("unroll")                                                     \
        for (int k = 0; k < 8; ++k) {                                         \
            float t_ = si + (k < 4 ? c0_[k & 3] : c1_[k & 3]);                \
            float lr_ = fmaxf(t_, 0.1f * t_);                                 \
            ev[k] = fmaf(lr_, (float)GC[k], QC[k >> 2][k & 3]);               \
        }                                                                     \
    } else {                                                                  \
        _Pragma("unroll")                                                     \
        for (int k = 0; k < 8; ++k) {                                         \
            float d_ = QC[k >> 2][k & 3];                                     \
            float A_ = __expf(-d_ * d_ * inv2s2);                             \
            float den_ = 1.0f + __expf(-10.0f * (A_ - th));                   \
            float r1_ = __builtin_amdgcn_rcpf(den_); r1_ = r1_ * (2.0f - den_ * r1_); \
            float dd_ = (jb_ + k == gi) ? 1.0f : d_;                          \
            float x2_ = dd_ + 1e-5f;                                          \
            float ri_ = __builtin_amdgcn_rcpf(x2_); ri_ = ri_ * (2.0f - x2_ * ri_);   \
            float t_ = si + (k < 4 ? c0_[k & 3] : c1_[k & 3]);                \
            float lr_ = fmaxf(t_, 0.1f * t_);                                 \
            ev[k] = (lr_ + ri_) * r1_;                                        \
        }                                                                     \
    }                                                                         \
    float mt_ = fmaxf(fmaxf(fmaxf(ev[0], ev[1]), fmaxf(ev[2], ev[3])),        \
                      fmaxf(fmaxf(ev[4], ev[5]), fmaxf(ev[6], ev[7])));       \
    mt_ = fmaxf(mt_, __shfl_xor(mt_, 1));                                     \
    mt_ = fmaxf(mt_, __shfl_xor(mt_, 2));                                     \
    mt_ = fmaxf(mt_, __shfl_xor(mt_, 4));                                     \
    const float mnew_ = fmaxf(m_r, mt_);                                      \
    float ps_ = 0.f; f16x8 pv_;                                               \
    _Pragma("unroll")                                                         \
    for (int k = 0; k < 8; ++k) {                                             \
        float p_ = __expf(ev[k] - mnew_);                                     \
        ps_ += p_; pv_[k] = (_Float16)p_;                                     \
    }                                                                         \
    ps_ += __shfl_xor(ps_, 1);                                                \
    ps_ += __shfl_xor(ps_, 2);                                                \
    ps_ += __shfl_xor(ps_, 4);                                                \
    *(f16x8*)(smem + (PB) * 4096 + row * 128 + ((jg ^ rsw) << 4)) = pv_;      \
    float scl_ = __expf(m_r - mnew_);                                         \
    if (jg == 0) scb[(PB) * 32 + row] = scl_;                                 \
    l_r = l_r * scl_ + ps_;                                                   \
    m_r = mnew_;                                                              \
}

#define WINDOW(HC, GC, QC, HN, GN, QN, JT, PB, MB) {                          \
    int jn_ = (JT) + 1; if (jn_ >= NT) jn_ = 0;                               \
    LOADT(HN, GN, QN, jn_ * 64);                                              \
    if ((JT) > 0) MFMA_STEP(MB);                                              \
    PHASE1(HC, GC, QC, (JT) * 64, PB);                                        \
    __syncthreads();                                                          \
}

    LOADT(hA, gA, qA, 0);
    for (int jt = 0; jt < NT; jt += 2) {
        WINDOW(hA, gA, qA, hB, gB, qB, jt,     0, 1);
        WINDOW(hB, gB, qB, hA, gA, qA, jt + 1, 1, 0);
    }
    if (jg == 0) lrow_s[row] = l_r;
    MFMA_STEP(1);
    __syncthreads();

    // epilogue: divide by l, f16 to ebuf, coalesced store
    _Float16* ebuf = (_Float16*)smem;
    #pragma unroll
    for (int m = 0; m < 2; ++m) {
        f32x4 lv = *(const f32x4*)&lrow_s[m * 16 + lq * 4];
        f32x4 inv;
        #pragma unroll
        for (int r = 0; r < 4; ++r) {
            float x = lv[r];
            float iv = __builtin_amdgcn_rcpf(x);
            inv[r] = iv * (2.0f - x * iv);
        }
        #pragma unroll
        for (int n = 0; n < 2; ++n)
            #pragma unroll
            for (int r = 0; r < 4; ++r)
                ebuf[(m * 16 + lq * 4 + r) * 128 + chq * 32 + n * 16 + lm] =
                    (_Float16)(acc[m][n][r] * inv[r]);
    }
    __syncthreads();
    {
        const int r = tid >> 3, c0 = (tid & 7) * 16;
        f16x8 v0 = *(const f16x8*)(ebuf + r * 128 + c0);
        f16x8 v1 = *(const f16x8*)(ebuf + r * 128 + c0 + 8);
        _Float16* dst = Hcat + ((size_t)(b * NN + i0 + r)) * (SS * HH) + s * HH + c0;
        *(f16x8*)dst = v0;
        *(f16x8*)(dst + 8) = v1;
    }
#undef LOADT
#undef MFMA_STEP
#undef PHASE1
#undef WINDOW
}

// ---------------------------------------------------------------------------
// fuse: out = Hcat(f16) @ fus_w^T + fus_b via fp16 MFMA. 32-row tiles, K=256.
// LDS: Hc [32][512B] @0 (16KB, XOR r&7), Wt [128][256B] @16384 (XOR ch&15).
// ---------------------------------------------------------------------------
__global__ __launch_bounds__(256, 2) void fuse_kernel(
    const _Float16* __restrict__ Hcat, const float* __restrict__ fw,
    const float* __restrict__ fb, float* __restrict__ out)
{
    const int r0 = blockIdx.x * 32;
    const int tid = threadIdx.x;
    __shared__ __align__(16) unsigned char smem[49152];

    {   // stage Hc full K=256 f16
        const int r = tid >> 3, q = tid & 7;
        const _Float16* src = Hcat + (size_t)(r0 + r) * 256 + q * 32;
        unsigned char* dst = smem + r * 512;
        const unsigned rs = r & 7;
        #pragma unroll
        for (int k = 0; k < 4; ++k) {
            f16x8 v = *(const f16x8*)(src + k * 8);
            *(f16x8*)(dst + (((q * 4 + k) ^ rs) << 4)) = v;
        }
    }

    const int wave = tid >> 6, lane = tid & 63;
    const int lm = lane & 15, lq = lane >> 4;
    f32x4 acc[2][2];
    #pragma unroll
    for (int m = 0; m < 2; ++m)
        #pragma unroll
        for (int n = 0; n < 2; ++n) acc[m][n] = (f32x4){0.f, 0.f, 0.f, 0.f};

    for (int c = 0; c < 2; ++c) {
        __syncthreads();
        {   // stage fus_w chunk (fp32->f16)
            const int ch = tid >> 1, kh8 = (tid & 1) * 8;
            const float* src = fw + (size_t)ch * 256 + c * 128 + kh8 * 8;
            unsigned char* dst = smem + 16384 + ch * 256;
            const unsigned cs = ch & 15;
            #pragma unroll
            for (int k = 0; k < 8; ++k) {
                float4 v0 = *(const float4*)(src + k * 8);
                float4 v1 = *(const float4*)(src + k * 8 + 4);
                f16x8 h;
                h[0]=(_Float16)v0.x; h[1]=(_Float16)v0.y; h[2]=(_Float16)v0.z; h[3]=(_Float16)v0.w;
                h[4]=(_Float16)v1.x; h[5]=(_Float16)v1.y; h[6]=(_Float16)v1.z; h[7]=(_Float16)v1.w;
                *(f16x8*)(dst + (((kh8 + k) ^ cs) << 4)) = h;
            }
        }
        __syncthreads();
        #pragma unroll
        for (int ks = 0; ks < 4; ++ks) {
            const int gks = c * 4 + ks;
            f16x8 af[2], bf[2];
            #pragma unroll
            for (int m = 0; m < 2; ++m) {
                int r = m * 16 + lm;
                af[m] = *(const f16x8*)(smem + r * 512 + ((((gks << 2) | lq) ^ (r & 7)) << 4));
            }
            #pragma unroll
            for (int n = 0; n < 2; ++n) {
                int ch = wave * 32 + n * 16 + lm;
                bf[n] = *(const f16x8*)(smem + 16384 + ch * 256 + ((((ks << 2) | lq) ^ (ch & 15)) << 4));
            }
            #pragma unroll
            for (int m = 0; m < 2; ++m)
                #pragma unroll
                for (int n = 0; n < 2; ++n)
                    acc[m][n] = __builtin_amdgcn_mfma_f32_16x16x32_f16(af[m], bf[n], acc[m][n], 0, 0, 0);
        }
    }
    {   // epilogue: + fus_b, fp32 store
        float fb0 = fb[wave * 32 + lm];
        float fb1 = fb[wave * 32 + 16 + lm];
        #pragma unroll
        for (int m = 0; m < 2; ++m)
            #pragma unroll
            for (int n = 0; n < 2; ++n) {
                float fbv = n ? fb1 : fb0;
                int ch = wave * 32 + n * 16 + lm;
                #pragma unroll
                for (int r = 0; r < 4; ++r)
                    out[(size_t)(r0 + m * 16 + lq * 4 + r) * HH + ch] = acc[m][n][r] + fbv;
            }
    }
}

// ---------------------------------------------------------------------------
extern "C" void kernel_launch(void* const* d_in, const int* in_sizes, int n_in,
                              void* d_out, int out_size, void* d_ws, size_t ws_size,
                              hipStream_t stream)
{
    const float* X      = (const float*)d_in[0];
    const float* dist   = (const float*)d_in[1];
    const float* sigmas = (const float*)d_in[2];
    const float* Ww     = (const float*)d_in[3];
    const float* Wb     = (const float*)d_in[4];
    const float* ai     = (const float*)d_in[5];
    const float* aj     = (const float*)d_in[6];
    const float* ab     = (const float*)d_in[7];
    const float* thr    = (const float*)d_in[8];
    const float* fw     = (const float*)d_in[9];
    const float* fb     = (const float*)d_in[10];
    float* out = (float*)d_out;

    // ws layout
    char* ws = (char*)d_ws;
    float*     srow = (float*)(ws);                    // 128 KB
    float*     scol = (float*)(ws + 131072);           // 128 KB
    _Float16*  h_t  = (_Float16*)(ws + 262144);        // 8 MB
    _Float16*  Hcat = (_Float16*)(ws + 8650752);       // 8 MB
    _Float16*  g1   = (_Float16*)(ws + 17039360);      // 16 MB
    float*     g2   = (float*)(ws + 33816576);         // 32 MB -> end 67371008
    const bool geo = ws_size >= (size_t)67371008;

    prep_kernel<<<dim3(NN / 64, BB, SS), 256, 0, stream>>>(X, Ww, Wb, ai, aj, ab, h_t, srow, scol);
    if (geo) {
        geo_kernel<<<(SS * NN * NN / 8) / 256, 256, 0, stream>>>(dist, sigmas, thr, g1, g2);
        attn_kernel<true><<<dim3(NN / 32, BB, SS), 256, 0, stream>>>(
            dist, sigmas, thr, h_t, srow, scol, g1, g2, Hcat);
    } else {
        attn_kernel<false><<<dim3(NN / 32, BB, SS), 256, 0, stream>>>(
            dist, sigmas, thr, h_t, srow, scol, (const _Float16*)nullptr, (const float*)nullptr, Hcat);
    }
    fuse_kernel<<<BB * NN / 32, 256, 0, stream>>>(Hcat, fw, fb, out);
}

// Round 5
// 190.257 us; speedup vs baseline: 1.0193x; 1.0193x over previous
//
#include <hip/hip_runtime.h>
#include <cstdint>
#include <cstddef>

#define BB 8
#define NN 2048
#define FF 128
#define HH 128
#define SS 2
#define NT (NN / 64)

typedef _Float16 f16x8 __attribute__((ext_vector_type(8)));
typedef _Float16 f16x4 __attribute__((ext_vector_type(4)));
typedef float f32x4 __attribute__((ext_vector_type(4)));

// ---------------------------------------------------------------------------
// prep: h = X@W^T (+Wb) via fp16 MFMA -> h_t[sb][ch][n] f16 (coalesced via LDS
// transpose). si/sj from MFMA accumulators; cross-wave reduce in LDS.
// LDS: Xs [64][256B] @0 (16KB, reused as hstage [128ch][64n]), Wt @16384
// (32KB), sred @49152 (2KB).
// ---------------------------------------------------------------------------
__global__ __launch_bounds__(256, 2) void prep_kernel(
    const float* __restrict__ X, const float* __restrict__ Ww, const float* __restrict__ Wb,
    const float* __restrict__ ai, const float* __restrict__ aj, const float* __restrict__ ab,
    _Float16* __restrict__ h_t, float* __restrict__ srow, float* __restrict__ scol)
{
    const int s = blockIdx.z, b = blockIdx.y;
    const int n0 = blockIdx.x * 64;
    const int tid = threadIdx.x;
    __shared__ __align__(16) unsigned char smem[51200];
    float* sredI = (float*)(smem + 49152);          // [4][64]
    float* sredJ = (float*)(smem + 49152 + 1024);   // [4][64]

    {   // stage Xs (fp32 -> f16, swizzled)
        const int r = tid >> 2, fq = tid & 3;
        const float* src = X + ((size_t)b * NN + n0 + r) * FF + fq * 32;
        unsigned char* dst = smem + r * 256;
        const unsigned rs = r & 15;
        #pragma unroll
        for (int k = 0; k < 4; ++k) {
            float4 v0 = *(const float4*)(src + k * 8);
            float4 v1 = *(const float4*)(src + k * 8 + 4);
            f16x8 h;
            h[0]=(_Float16)v0.x; h[1]=(_Float16)v0.y; h[2]=(_Float16)v0.z; h[3]=(_Float16)v0.w;
            h[4]=(_Float16)v1.x; h[5]=(_Float16)v1.y; h[6]=(_Float16)v1.z; h[7]=(_Float16)v1.w;
            *(f16x8*)(dst + (((fq * 4 + k) ^ rs) << 4)) = h;
        }
    }
    {   // stage Wt (fp32 -> f16, swizzled)
        const int ch = tid >> 1, kh8 = (tid & 1) * 8;
        const float* src = Ww + ((size_t)s * HH + ch) * FF + kh8 * 8;
        unsigned char* dst = smem + 16384 + ch * 256;
        const unsigned cs = ch & 15;
        #pragma unroll
        for (int k = 0; k < 8; ++k) {
            float4 v0 = *(const float4*)(src + k * 8);
            float4 v1 = *(const float4*)(src + k * 8 + 4);
            f16x8 h;
            h[0]=(_Float16)v0.x; h[1]=(_Float16)v0.y; h[2]=(_Float16)v0.z; h[3]=(_Float16)v0.w;
            h[4]=(_Float16)v1.x; h[5]=(_Float16)v1.y; h[6]=(_Float16)v1.z; h[7]=(_Float16)v1.w;
            *(f16x8*)(dst + (((kh8 + k) ^ cs) << 4)) = h;
        }
    }
    __syncthreads();

    const int wave = tid >> 6, lane = tid & 63;
    const int lm = lane & 15, lq = lane >> 4;
    f32x4 acc[4][2];
    #pragma unroll
    for (int m = 0; m < 4; ++m)
        #pragma unroll
        for (int n = 0; n < 2; ++n) acc[m][n] = (f32x4){0.f, 0.f, 0.f, 0.f};

    #pragma unroll
    for (int ks = 0; ks < 4; ++ks) {
        f16x8 af[4], bf[2];
        #pragma unroll
        for (int m = 0; m < 4; ++m) {
            int r = m * 16 + lm;
            af[m] = *(const f16x8*)(smem + r * 256 + ((((ks << 2) | lq) ^ (r & 15)) << 4));
        }
        #pragma unroll
        for (int n = 0; n < 2; ++n) {
            int ch = wave * 32 + n * 16 + lm;
            bf[n] = *(const f16x8*)(smem + 16384 + ch * 256 + ((((ks << 2) | lq) ^ (ch & 15)) << 4));
        }
        #pragma unroll
        for (int m = 0; m < 4; ++m)
            #pragma unroll
            for (int n = 0; n < 2; ++n)
                acc[m][n] = __builtin_amdgcn_mfma_f32_16x16x32_f16(af[m], bf[n], acc[m][n], 0, 0, 0);
    }

    const float wb0 = Wb[s * HH + wave * 32 + lm];
    const float wb1 = Wb[s * HH + wave * 32 + 16 + lm];
    const float ai0 = ai[s * HH + wave * 32 + lm];
    const float ai1 = ai[s * HH + wave * 32 + 16 + lm];
    const float aj0 = aj[s * HH + wave * 32 + lm];
    const float aj1 = aj[s * HH + wave * 32 + 16 + lm];
    float pI[4][4], pJ[4][4];
    #pragma unroll
    for (int m = 0; m < 4; ++m)
        #pragma unroll
        for (int r = 0; r < 4; ++r) {
            float h0 = acc[m][0][r] + wb0;
            float h1 = acc[m][1][r] + wb1;
            pI[m][r] = h0 * ai0 + h1 * ai1;
            pJ[m][r] = h0 * aj0 + h1 * aj1;
        }
    #pragma unroll
    for (int st = 1; st < 16; st <<= 1) {
        #pragma unroll
        for (int m = 0; m < 4; ++m)
            #pragma unroll
            for (int r = 0; r < 4; ++r) {
                pI[m][r] += __shfl_xor(pI[m][r], st);
                pJ[m][r] += __shfl_xor(pJ[m][r], st);
            }
    }
    __syncthreads();   // Xs region dead: MFMA reads complete

    {   // stage h transposed into LDS [128 ch][64 n] f16 (swizzled)
        #pragma unroll
        for (int m = 0; m < 4; ++m)
            #pragma unroll
            for (int n = 0; n < 2; ++n) {
                float wb = n ? wb1 : wb0;
                f16x4 hv;
                #pragma unroll
                for (int r = 0; r < 4; ++r) hv[r] = (_Float16)(acc[m][n][r] + wb);
                int ch = wave * 32 + n * 16 + lm;
                int slot = m * 2 + (lq >> 1);
                *(f16x4*)(smem + ch * 128 + ((slot ^ (ch & 7)) << 4) + (lq & 1) * 8) = hv;
            }
    }
    if (lm == 0) {
        #pragma unroll
        for (int m = 0; m < 4; ++m)
            #pragma unroll
            for (int r = 0; r < 4; ++r) {
                sredI[wave * 64 + m * 16 + lq * 4 + r] = pI[m][r];
                sredJ[wave * 64 + m * 16 + lq * 4 + r] = pJ[m][r];
            }
    }
    __syncthreads();
    {   // coalesced h_t store
        const int ch = tid >> 1, half = tid & 1;
        _Float16* dst = h_t + ((size_t)((s * BB + b) * HH + ch)) * NN + n0 + half * 32;
        const unsigned cs = ch & 7;
        #pragma unroll
        for (int k = 0; k < 4; ++k) {
            f16x8 v = *(const f16x8*)(smem + ch * 128 + (((half * 4 + k) ^ cs) << 4));
            *(f16x8*)(dst + k * 8) = v;
        }
    }
    if (tid < 64) {
        float sI = sredI[tid] + sredI[64 + tid] + sredI[128 + tid] + sredI[192 + tid] + ab[s];
        float sJ = sredJ[tid] + sredJ[64 + tid] + sredJ[128 + tid] + sredJ[192 + tid];
        size_t idx = (size_t)(s * BB + b) * NN + n0 + tid;
        srow[idx] = sI;
        scol[idx] = sJ;
    }
}

// ---------------------------------------------------------------------------
// attn: fused flash, b-PAIR per block (geo math computed once, shared by 2
// batches). 512 thr = 8 waves. TM=32 rows, TK=64. Grid 512 = (s,bpair)%8
// [XCD-pinned: each XCD's L2 caches its two 512KB h_t panels] x 64 i-tiles.
// e = mask*(leaky(si+sj) + inv_d): mask/inv_d inline (no geo arrays).
// LDS: P[2b][32][128B] @0 (8KB), h[2b][128ch][128B] @8192 (32KB),
//      scb @40960 (256B), lrow @41216 (256B). Epilogue ebuf reuses @0.
// ---------------------------------------------------------------------------
__global__ __launch_bounds__(512, 4) void attn_kernel(
    const float* __restrict__ dist, const float* __restrict__ sigmas,
    const float* __restrict__ thr, const _Float16* __restrict__ h_t,
    const float* __restrict__ srow, const float* __restrict__ scol,
    _Float16* __restrict__ Hcat)
{
    const int bx = blockIdx.x;
    const int grp = bx & 7;                  // (s, bpair) -> XCD
    const int i0 = (bx >> 3) * 32;
    const int s = grp >> 2;
    const int b0 = (grp & 3) * 2;

    __shared__ __align__(16) unsigned char smem[41472];
    float* scb  = (float*)(smem + 40960);    // [2][32] rescale factors
    float* lrow = (float*)(smem + 41216);    // [2][32] final l

    const int tid = threadIdx.x;
    const int wave = tid >> 6, lane = tid & 63;
    const int lm = lane & 15, lq = lane >> 4;

    const float sg = sigmas[s];
    const float inv2s2 = 1.0f / (2.0f * sg * sg);
    const float th = thr[s];

    // phase-1 geometry: 32 rows x 16 j-groups of 4
    const int row = tid >> 4, jq = tid & 15;
    const int gi = i0 + row;
    const size_t sb0 = (size_t)(s * BB + b0) * NN;
    const size_t sb1 = sb0 + NN;
    const float si0 = srow[sb0 + gi];
    const float si1 = srow[sb1 + gi];
    const float* drow = dist + (size_t)gi * NN;

    // h-stage geometry: ch = tid>>2, slot = tid&3 (and +4)
    const int sch = tid >> 2, sq = tid & 3;
    const _Float16* hb0 = h_t + ((size_t)((s * BB + b0) * HH + sch)) * NN;
    const _Float16* hb1 = hb0 + (size_t)HH * NN;
    unsigned char* hd0 = smem + 8192 + sch * 128;
    unsigned char* hd1 = hd0 + 16384;
    const unsigned hsw = sch & 7;

    // MFMA: wave -> (b of pair, ch-quarter)
    const int wb = wave >> 2, cq = wave & 3;

    f32x4 acc[2][2];
    #pragma unroll
    for (int m = 0; m < 2; ++m)
        #pragma unroll
        for (int n = 0; n < 2; ++n) acc[m][n] = (f32x4){0.f, 0.f, 0.f, 0.f};
    float m0 = -3.0e38f, m1 = -3.0e38f, l0 = 0.f, l1 = 0.f;

    for (int jt = 0; jt < NT; ++jt) {
        const int j0 = jt * 64;
        // issue h loads early (L2 hits; consumed at end of phase-1)
        f16x8 hv00 = *(const f16x8*)(hb0 + j0 + sq * 8);
        f16x8 hv01 = *(const f16x8*)(hb0 + j0 + 32 + sq * 8);
        f16x8 hv10 = *(const f16x8*)(hb1 + j0 + sq * 8);
        f16x8 hv11 = *(const f16x8*)(hb1 + j0 + 32 + sq * 8);

        // ---------------- phase 1: e for both b (geo math shared)
        const int jb = j0 + jq * 4;
        f32x4 dv = *(const f32x4*)(drow + jb);
        f32x4 c0 = *(const f32x4*)(scol + sb0 + jb);
        f32x4 c1 = *(const f32x4*)(scol + sb1 + jb);
        float e0[4], e1[4];
        #pragma unroll
        for (int k = 0; k < 4; ++k) {
            float d = dv[k];
            float A = __expf(-d * d * inv2s2);
            float den = 1.0f + __expf(-10.0f * (A - th));
            float msk = __builtin_amdgcn_rcpf(den);
            float dd = (jb + k == gi) ? 1.0f : d;
            float x2 = dd + 1e-5f;
            float ri = __builtin_amdgcn_rcpf(x2);
            ri = ri * (2.0f - x2 * ri);          // NR: inv_d needs abs precision
            float t0 = si0 + c0[k]; t0 = fmaxf(t0, 0.1f * t0);
            float t1 = si1 + c1[k]; t1 = fmaxf(t1, 0.1f * t1);
            e0[k] = (t0 + ri) * msk;
            e1[k] = (t1 + ri) * msk;
        }
        float mt0 = fmaxf(fmaxf(e0[0], e0[1]), fmaxf(e0[2], e0[3]));
        float mt1 = fmaxf(fmaxf(e1[0], e1[1]), fmaxf(e1[2], e1[3]));
        #pragma unroll
        for (int st = 1; st < 16; st <<= 1) {
            mt0 = fmaxf(mt0, __shfl_xor(mt0, st));
            mt1 = fmaxf(mt1, __shfl_xor(mt1, st));
        }
        const float mn0 = fmaxf(m0, mt0), mn1 = fmaxf(m1, mt1);
        f16x4 pv0, pv1;
        float ps0 = 0.f, ps1 = 0.f;
        #pragma unroll
        for (int k = 0; k < 4; ++k) {
            float p0 = __expf(e0[k] - mn0); ps0 += p0; pv0[k] = (_Float16)p0;
            float p1 = __expf(e1[k] - mn1); ps1 += p1; pv1[k] = (_Float16)p1;
        }
        #pragma unroll
        for (int st = 1; st < 16; st <<= 1) {
            ps0 += __shfl_xor(ps0, st);
            ps1 += __shfl_xor(ps1, st);
        }
        {
            const unsigned off = row * 128 + (((jq >> 1) ^ (row & 7)) << 4) + (jq & 1) * 8;
            *(f16x4*)(smem + off) = pv0;
            *(f16x4*)(smem + 4096 + off) = pv1;
        }
        float scl0 = __expf(m0 - mn0), scl1 = __expf(m1 - mn1);
        l0 = l0 * scl0 + ps0; m0 = mn0;
        l1 = l1 * scl1 + ps1; m1 = mn1;
        if (jq == 0) { scb[row] = scl0; scb[32 + row] = scl1; }

        // h -> LDS (swizzled)
        *(f16x8*)(hd0 + ((sq ^ hsw) << 4)) = hv00;
        *(f16x8*)(hd0 + (((sq + 4) ^ hsw) << 4)) = hv01;
        *(f16x8*)(hd1 + ((sq ^ hsw) << 4)) = hv10;
        *(f16x8*)(hd1 + (((sq + 4) ^ hsw) << 4)) = hv11;
        __syncthreads();

        // ---------------- MFMA: wave's batch = wb
        {
            const unsigned char* Pb = smem + wb * 4096;
            const unsigned char* Hb = smem + 8192 + wb * 16384;
            const int ra = lm;           const unsigned sa = ra & 7;
            const int rb = 16 + lm;      const unsigned sbw = rb & 7;
            f16x8 a00 = *(const f16x8*)(Pb + ra * 128 + ((lq ^ sa) << 4));
            f16x8 a01 = *(const f16x8*)(Pb + ra * 128 + (((4 | lq) ^ sa) << 4));
            f16x8 a10 = *(const f16x8*)(Pb + rb * 128 + ((lq ^ sbw) << 4));
            f16x8 a11 = *(const f16x8*)(Pb + rb * 128 + (((4 | lq) ^ sbw) << 4));
            const int ca = cq * 32 + lm;      const unsigned ta = ca & 7;
            const int cb = cq * 32 + 16 + lm; const unsigned tb = cb & 7;
            f16x8 b00 = *(const f16x8*)(Hb + ca * 128 + ((lq ^ ta) << 4));
            f16x8 b01 = *(const f16x8*)(Hb + ca * 128 + (((4 | lq) ^ ta) << 4));
            f16x8 b10 = *(const f16x8*)(Hb + cb * 128 + ((lq ^ tb) << 4));
            f16x8 b11 = *(const f16x8*)(Hb + cb * 128 + (((4 | lq) ^ tb) << 4));
            f32x4 sA = *(const f32x4*)(scb + wb * 32 + lq * 4);
            f32x4 sB = *(const f32x4*)(scb + wb * 32 + 16 + lq * 4);
            acc[0][0] *= sA; acc[0][1] *= sA;
            acc[1][0] *= sB; acc[1][1] *= sB;
            acc[0][0] = __builtin_amdgcn_mfma_f32_16x16x32_f16(a00, b00, acc[0][0], 0, 0, 0);
            acc[0][0] = __builtin_amdgcn_mfma_f32_16x16x32_f16(a01, b01, acc[0][0], 0, 0, 0);
            acc[0][1] = __builtin_amdgcn_mfma_f32_16x16x32_f16(a00, b10, acc[0][1], 0, 0, 0);
            acc[0][1] = __builtin_amdgcn_mfma_f32_16x16x32_f16(a01, b11, acc[0][1], 0, 0, 0);
            acc[1][0] = __builtin_amdgcn_mfma_f32_16x16x32_f16(a10, b00, acc[1][0], 0, 0, 0);
            acc[1][0] = __builtin_amdgcn_mfma_f32_16x16x32_f16(a11, b01, acc[1][0], 0, 0, 0);
            acc[1][1] = __builtin_amdgcn_mfma_f32_16x16x32_f16(a10, b10, acc[1][1], 0, 0, 0);
            acc[1][1] = __builtin_amdgcn_mfma_f32_16x16x32_f16(a11, b11, acc[1][1], 0, 0, 0);
        }
        __syncthreads();
    }

    if (jq == 0) { lrow[row] = l0; lrow[32 + row] = l1; }
    __syncthreads();

    // epilogue: /l, f16 into ebuf [2b][32][128], coalesced store
    _Float16* ebuf = (_Float16*)smem;
    {
        f32x4 lvA = *(const f32x4*)(lrow + wb * 32 + lq * 4);
        f32x4 lvB = *(const f32x4*)(lrow + wb * 32 + 16 + lq * 4);
        f32x4 iA, iB;
        #pragma unroll
        for (int r = 0; r < 4; ++r) {
            float xa = lvA[r], xb = lvB[r];
            float va = __builtin_amdgcn_rcpf(xa); iA[r] = va * (2.0f - xa * va);
            float vb = __builtin_amdgcn_rcpf(xb); iB[r] = vb * (2.0f - xb * vb);
        }
        #pragma unroll
        for (int m = 0; m < 2; ++m)
            #pragma unroll
            for (int n = 0; n < 2; ++n)
                #pragma unroll
                for (int r = 0; r < 4; ++r) {
                    float inv = m ? iB[r] : iA[r];
                    ebuf[wb * 4096 + (m * 16 + lq * 4 + r) * 128 + cq * 32 + n * 16 + lm] =
                        (_Float16)(acc[m][n][r] * inv);
                }
    }
    __syncthreads();
    #pragma unroll
    for (int rep = 0; rep < 2; ++rep) {
        const int idx = tid + rep * 512;
        const int eb = idx >> 9, erow = (idx >> 4) & 31, u = idx & 15;
        f16x8 v = *(const f16x8*)(ebuf + eb * 4096 + erow * 128 + u * 8);
        *(f16x8*)(Hcat + ((size_t)((b0 + eb) * NN + i0 + erow)) * (SS * HH) + s * HH + u * 8) = v;
    }
}

// ---------------------------------------------------------------------------
// fuse: out = Hcat(f16) @ fus_w^T + fus_b via fp16 MFMA. 32-row tiles, K=256.
// ---------------------------------------------------------------------------
__global__ __launch_bounds__(256, 2) void fuse_kernel(
    const _Float16* __restrict__ Hcat, const float* __restrict__ fw,
    const float* __restrict__ fb, float* __restrict__ out)
{
    const int r0 = blockIdx.x * 32;
    const int tid = threadIdx.x;
    __shared__ __align__(16) unsigned char smem[49152];

    {   // stage Hc full K=256 f16
        const int r = tid >> 3, q = tid & 7;
        const _Float16* src = Hcat + (size_t)(r0 + r) * 256 + q * 32;
        unsigned char* dst = smem + r * 512;
        const unsigned rs = r & 7;
        #pragma unroll
        for (int k = 0; k < 4; ++k) {
            f16x8 v = *(const f16x8*)(src + k * 8);
            *(f16x8*)(dst + (((q * 4 + k) ^ rs) << 4)) = v;
        }
    }

    const int wave = tid >> 6, lane = tid & 63;
    const int lm = lane & 15, lq = lane >> 4;
    f32x4 acc[2][2];
    #pragma unroll
    for (int m = 0; m < 2; ++m)
        #pragma unroll
        for (int n = 0; n < 2; ++n) acc[m][n] = (f32x4){0.f, 0.f, 0.f, 0.f};

    for (int c = 0; c < 2; ++c) {
        __syncthreads();
        {   // stage fus_w chunk (fp32->f16)
            const int ch = tid >> 1, kh8 = (tid & 1) * 8;
            const float* src = fw + (size_t)ch * 256 + c * 128 + kh8 * 8;
            unsigned char* dst = smem + 16384 + ch * 256;
            const unsigned cs = ch & 15;
            #pragma unroll
            for (int k = 0; k < 8; ++k) {
                float4 v0 = *(const float4*)(src + k * 8);
                float4 v1 = *(const float4*)(src + k * 8 + 4);
                f16x8 h;
                h[0]=(_Float16)v0.x; h[1]=(_Float16)v0.y; h[2]=(_Float16)v0.z; h[3]=(_Float16)v0.w;
                h[4]=(_Float16)v1.x; h[5]=(_Float16)v1.y; h[6]=(_Float16)v1.z; h[7]=(_Float16)v1.w;
                *(f16x8*)(dst + (((kh8 + k) ^ cs) << 4)) = h;
            }
        }
        __syncthreads();
        #pragma unroll
        for (int ks = 0; ks < 4; ++ks) {
            const int gks = c * 4 + ks;
            f16x8 af[2], bf[2];
            #pragma unroll
            for (int m = 0; m < 2; ++m) {
                int r = m * 16 + lm;
                af[m] = *(const f16x8*)(smem + r * 512 + ((((gks << 2) | lq) ^ (r & 7)) << 4));
            }
            #pragma unroll
            for (int n = 0; n < 2; ++n) {
                int ch = wave * 32 + n * 16 + lm;
                bf[n] = *(const f16x8*)(smem + 16384 + ch * 256 + ((((ks << 2) | lq) ^ (ch & 15)) << 4));
            }
            #pragma unroll
            for (int m = 0; m < 2; ++m)
                #pragma unroll
                for (int n = 0; n < 2; ++n)
                    acc[m][n] = __builtin_amdgcn_mfma_f32_16x16x32_f16(af[m], bf[n], acc[m][n], 0, 0, 0);
        }
    }
    {   // epilogue: + fus_b, fp32 store
        float fb0 = fb[wave * 32 + lm];
        float fb1 = fb[wave * 32 + 16 + lm];
        #pragma unroll
        for (int m = 0; m < 2; ++m)
            #pragma unroll
            for (int n = 0; n < 2; ++n) {
                float fbv = n ? fb1 : fb0;
                int ch = wave * 32 + n * 16 + lm;
                #pragma unroll
                for (int r = 0; r < 4; ++r)
                    out[(size_t)(r0 + m * 16 + lq * 4 + r) * HH + ch] = acc[m][n][r] + fbv;
            }
    }
}

// ---------------------------------------------------------------------------
extern "C" void kernel_launch(void* const* d_in, const int* in_sizes, int n_in,
                              void* d_out, int out_size, void* d_ws, size_t ws_size,
                              hipStream_t stream)
{
    const float* X      = (const float*)d_in[0];
    const float* dist   = (const float*)d_in[1];
    const float* sigmas = (const float*)d_in[2];
    const float* Ww     = (const float*)d_in[3];
    const float* Wb     = (const float*)d_in[4];
    const float* ai     = (const float*)d_in[5];
    const float* aj     = (const float*)d_in[6];
    const float* ab     = (const float*)d_in[7];
    const float* fw     = (const float*)d_in[9];
    const float* fb     = (const float*)d_in[10];
    const float* thr    = (const float*)d_in[8];
    float* out = (float*)d_out;

    // ws layout (~16.3 MB)
    char* ws = (char*)d_ws;
    float*     srow = (float*)(ws);                    // 128 KB
    float*     scol = (float*)(ws + 131072);           // 128 KB
    _Float16*  h_t  = (_Float16*)(ws + 262144);        // 8 MB
    _Float16*  Hcat = (_Float16*)(ws + 8650752);       // 8 MB -> end 17039360

    prep_kernel<<<dim3(NN / 64, BB, SS), 256, 0, stream>>>(X, Ww, Wb, ai, aj, ab, h_t, srow, scol);
    attn_kernel<<<512, 512, 0, stream>>>(dist, sigmas, thr, h_t, srow, scol, Hcat);
    fuse_kernel<<<BB * NN / 32, 256, 0, stream>>>(Hcat, fw, fb, out);
}